// Round 13
// baseline (229.710 us; speedup 1.0000x reference)
//
#include <hip/hip_runtime.h>
#include <hip/hip_bf16.h>
#include <hip/hip_fp16.h>

typedef __attribute__((ext_vector_type(4))) float f32x4;
typedef _Float16 h8 __attribute__((ext_vector_type(8)));
typedef int i32x4 __attribute__((ext_vector_type(4)));
typedef _Float16 h2 __attribute__((ext_vector_type(2)));

static __device__ __forceinline__ h2 ih2(int x) { return __builtin_bit_cast(h2, x); }
static __device__ __forceinline__ unsigned pkrtz(float lo, float hi) {
  return __builtin_bit_cast(unsigned, __builtin_amdgcn_cvt_pkrtz(lo, hi));
}
// inline-asm packed f16 ops
static __device__ __forceinline__ int pkmin(int x, int y) {
  int d; asm("v_pk_min_f16 %0, %1, %2" : "=v"(d) : "v"(x), "v"(y)); return d;
}
static __device__ __forceinline__ int pkmax(int x, int y) {
  int d; asm("v_pk_max_f16 %0, %1, %2" : "=v"(d) : "v"(x), "v"(y)); return d;
}
static __device__ __forceinline__ int pkadd(int x, int y) {
  int d; asm("v_pk_add_f16 %0, %1, %2" : "=v"(d) : "v"(x), "v"(y)); return d;
}

// Problem constants: B=32, L=64, C=128, D=512, O=256, L2=4096

// ------ K1 (fused prep): u,v = f16(x@w1 split + b1); w2t; pwt ------------
__global__ __launch_bounds__(256) void k_prep(const float* __restrict__ x,
                                              const float* __restrict__ w1,
                                              const float* __restrict__ b1,
                                              const float* __restrict__ w2,
                                              const float* __restrict__ pw,
                                              _Float16* __restrict__ u,
                                              _Float16* __restrict__ v,
                                              _Float16* __restrict__ w2t,
                                              float* __restrict__ pwt) {
  __shared__ float xs[8 * 128];
  int bid = blockIdx.x;
  int t = threadIdx.x;
  if (bid < 256) {
    int r0 = bid * 8;
    ((float4*)xs)[t] = ((const float4*)(x + (size_t)r0 * 128))[t];
    __syncthreads();
    int d1 = t, d2 = t + 256;
    float au0[8], au1[8], av0[8], av1[8];
    float bb1 = b1[d1], bb2 = b1[d2];
#pragma unroll
    for (int r = 0; r < 8; ++r) { au0[r] = bb1; au1[r] = bb2; av0[r] = 0.f; av1[r] = 0.f; }
#pragma unroll 4
    for (int c = 0; c < 128; ++c) {
      float wu1 = w1[c * 512 + d1];
      float wu2 = w1[c * 512 + d2];
      float wv1 = w1[(c + 128) * 512 + d1];
      float wv2 = w1[(c + 128) * 512 + d2];
#pragma unroll
      for (int r = 0; r < 8; ++r) {
        float xv = xs[r * 128 + c];
        au0[r] = fmaf(xv, wu1, au0[r]);
        au1[r] = fmaf(xv, wu2, au1[r]);
        av0[r] = fmaf(xv, wv1, av0[r]);
        av1[r] = fmaf(xv, wv2, av1[r]);
      }
    }
#pragma unroll
    for (int r = 0; r < 8; ++r) {
      u[(size_t)(r0 + r) * 512 + d1] = (_Float16)au0[r];
      u[(size_t)(r0 + r) * 512 + d2] = (_Float16)au1[r];
      v[(size_t)(r0 + r) * 512 + d1] = (_Float16)av0[r];
      v[(size_t)(r0 + r) * 512 + d2] = (_Float16)av1[r];
    }
  } else if (bid < 512) {
    int n = bid - 256;
    w2t[(size_t)n * 512 + t]       = (_Float16)w2[(size_t)t * 256 + n];
    w2t[(size_t)n * 512 + t + 256] = (_Float16)w2[(size_t)(t + 256) * 256 + n];
  } else {
    int o = bid - 512;
#pragma unroll
    for (int it = 0; it < 16; ++it) {
      int l = it * 256 + t;
      pwt[(size_t)o * 4096 + l] = pw[(size_t)l * 256 + o];
    }
  }
}

// ---- K4: one (b,i) per block; wave = (j-half, col-half); ni=8 reuse ----
__global__ __launch_bounds__(256, 2) void k_gemm(const _Float16* __restrict__ u,
                                                 const _Float16* __restrict__ v,
                                                 const _Float16* __restrict__ w2t,
                                                 const float* __restrict__ b2,
                                                 unsigned short* __restrict__ yt) {
  __shared__ char vl[64 * 1024];  // 64 rows x 512 f16, XOR-swizzled
  __shared__ char ulm[1024];      // 1 u-row x 512 f16
  int t = threadIdx.x;
  int n0 = blockIdx.x;                      // 2048 blocks
  int bid = (n0 & 7) * 256 + (n0 >> 3);     // XCD-bijective: same-b same XCD
  int b = bid >> 6, i = bid & 63;
  {
    const char* vsrc = (const char*)(v + (size_t)b * 64 * 512);
#pragma unroll
    for (int it = 0; it < 16; ++it) {
      int f = it * 4096 + t * 16;
      uint4 d = *(const uint4*)(vsrc + f);
      int row = f >> 10;
      *(uint4*)(vl + (f ^ ((row & 7) << 4))) = d;
    }
    if (t < 64) {
      const char* usrc = (const char*)(u + (size_t)(b * 64 + i) * 512);
      *(uint4*)(ulm + t * 16) = *(const uint4*)(usrc + t * 16);
    }
  }
  __syncthreads();
  int w = t >> 6, l = t & 63, lr = l & 15, lg = l >> 4;
  int jh = w & 1, nh = w >> 1;              // j rows 32*jh.., cols 128*nh..
  const _Float16* bptr[8];
  f32x4 acc[2][8];
#pragma unroll
  for (int ni = 0; ni < 8; ++ni) {
    int col = nh * 128 + ni * 16 + lr;
    bptr[ni] = w2t + (size_t)col * 512 + lg * 8;
    float bv = b2[col];
    f32x4 ci = {bv, bv, bv, bv};
    acc[0][ni] = ci;
    acc[1][ni] = ci;
  }
#pragma unroll 4
  for (int kk = 0; kk < 16; ++kk) {
    h8 bfv[8];
#pragma unroll
    for (int ni = 0; ni < 8; ++ni) bfv[ni] = *(const h8*)(bptr[ni] + kk * 32);
    i32x4 uf = *(const i32x4*)(ulm + kk * 64 + lg * 16);
    h8 af[2];
#pragma unroll
    for (int mi = 0; mi < 2; ++mi) {
      int row = jh * 32 + mi * 16 + lr;
      int fb = row * 1024 + kk * 64 + lg * 16;
      i32x4 vf = *(const i32x4*)(vl + (fb ^ ((row & 7) << 4)));
      i32x4 aw;
#pragma unroll
      for (int q = 0; q < 4; ++q) aw[q] = pkmax(pkadd(uf[q], vf[q]), 0);
      af[mi] = __builtin_bit_cast(h8, aw);
    }
#pragma unroll
    for (int mi = 0; mi < 2; ++mi)
#pragma unroll
      for (int ni = 0; ni < 8; ++ni)
        acc[mi][ni] = __builtin_amdgcn_mfma_f32_16x16x32_f16(af[mi], bfv[ni], acc[mi][ni], 0, 0, 0);
  }
  // epilogue: n = col (lane&15), j = jh*32 + mi*16 + lg*4 + reg
#pragma unroll
  for (int mi = 0; mi < 2; ++mi)
#pragma unroll
    for (int ni = 0; ni < 8; ++ni) {
      int col = nh * 128 + ni * 16 + lr;
      unsigned short* colbase =
          yt + (size_t)(b * 256 + col) * 4096 + (size_t)i * 64 + jh * 32 + mi * 16 + lg * 4;
      f32x4 vv = acc[mi][ni];
      uint2 st;
      st.x = pkrtz(vv[0], vv[1]);
      st.y = pkrtz(vv[2], vv[3]);
      *(uint2*)colbase = st;
    }
}

// ----- K5: E=64 single-wave packed-f16 bitonic sort + pool (no LDS) -----
#define DPP_X1 0xB1   // quad_perm [1,0,3,2]  : lane^1
#define DPP_X2 0x4E   // quad_perm [2,3,0,1]  : lane^2
#define DPP_X3 0x1B   // quad_perm [3,2,1,0]  : lane^3
#define DPP_X7 0x141  // row_half_mirror      : lane^7
#define DPP_X8 0x128  // row_ror:8            : lane^8
#define DPP_XF 0x140  // row_mirror           : lane^15

// intra-register CE pass: pairs (e, e^M), min at low index
template <int M, int HB>
static __device__ __forceinline__ void intra(int* a) {
#pragma unroll
  for (int e = 0; e < 64; ++e)
    if ((e & HB) == 0) {
      int f = e ^ M;
      int lo = pkmin(a[e], a[f]);
      int hi = pkmax(a[e], a[f]);
      a[e] = lo;
      a[f] = hi;
    }
}

// clean cross pass via DPP (same e, partner lane)
template <int CTRL>
static __device__ __forceinline__ void cdpp(int* a, bool km) {
#pragma unroll
  for (int e = 0; e < 64; ++e) {
    int r = __builtin_amdgcn_mov_dpp(a[e], CTRL, 0xf, 0xf, true);
    int mn = pkmin(a[e], r), mx = pkmax(a[e], r);
    a[e] = km ? mn : mx;
  }
}

// flip cross pass via DPP (e^63, partner lane)
template <int CTRL>
static __device__ __forceinline__ void fdpp(int* a, bool km) {
#pragma unroll
  for (int e = 0; e < 32; ++e) {
    int f = e ^ 63;
    int r0 = __builtin_amdgcn_mov_dpp(a[f], CTRL, 0xf, 0xf, true);
    int r1 = __builtin_amdgcn_mov_dpp(a[e], CTRL, 0xf, 0xf, true);
    int mn0 = pkmin(a[e], r0), mx0 = pkmax(a[e], r0);
    int mn1 = pkmin(a[f], r1), mx1 = pkmax(a[f], r1);
    a[e] = km ? mn0 : mx0;
    a[f] = km ? mn1 : mx1;
  }
}

// clean cross pass via ds_bpermute
static __device__ __forceinline__ void cbp(int* a, int tm, bool km, int l) {
  int paddr = ((l ^ tm) & 63) << 2;
#pragma unroll
  for (int e = 0; e < 64; ++e) {
    int r = __builtin_amdgcn_ds_bpermute(paddr, a[e]);
    int mn = pkmin(a[e], r), mx = pkmax(a[e], r);
    a[e] = km ? mn : mx;
  }
}

// flip cross pass via ds_bpermute (e^63)
static __device__ __forceinline__ void fbp(int* a, int tm, bool km, int l) {
  int paddr = ((l ^ tm) & 63) << 2;
#pragma unroll
  for (int e = 0; e < 32; ++e) {
    int f = e ^ 63;
    int r0 = __builtin_amdgcn_ds_bpermute(paddr, a[f]);
    int r1 = __builtin_amdgcn_ds_bpermute(paddr, a[e]);
    int mn0 = pkmin(a[e], r0), mx0 = pkmax(a[e], r0);
    int mn1 = pkmin(a[f], r1), mx1 = pkmax(a[f], r1);
    a[e] = km ? mn0 : mx0;
    a[f] = km ? mn1 : mx1;
  }
}

__global__ __launch_bounds__(64) void k_sortpool(const unsigned short* __restrict__ yt,
                                                 const float* __restrict__ pwt,
                                                 float* __restrict__ out) {
  int t = threadIdx.x;  // lane 0..63 (one wave per block)
  int b = blockIdx.x >> 7, p = blockIdx.x & 127;
  int o0 = p * 2, o1 = o0 + 1;
  const uint4* c0 = (const uint4*)(yt + (size_t)(b * 256 + o0) * 4096 + t * 64);
  const uint4* c1 = (const uint4*)(yt + (size_t)(b * 256 + o1) * 4096 + t * 64);
  int a[64];
#pragma unroll
  for (int q = 0; q < 8; ++q) {  // 8 elems per uint4 per column
    uint4 x0 = c0[q], x1 = c1[q];
    unsigned w0[4] = {x0.x, x0.y, x0.z, x0.w};
    unsigned w1[4] = {x1.x, x1.y, x1.z, x1.w};
#pragma unroll
    for (int r = 0; r < 4; ++r) {
      a[q * 8 + 2 * r]     = (int)((w0[r] & 0xffffu) | (w1[r] << 16));
      a[q * 8 + 2 * r + 1] = (int)((w0[r] >> 16) | (w1[r] & 0xffff0000u));
    }
  }
  // stages s1..s6 (runs <= 64): pure in-register
  intra<1, 1>(a);
  intra<3, 2>(a); intra<1, 1>(a);
  intra<7, 4>(a); intra<2, 2>(a); intra<1, 1>(a);
  intra<15, 8>(a); intra<4, 4>(a); intra<2, 2>(a); intra<1, 1>(a);
  intra<31, 16>(a); intra<8, 8>(a); intra<4, 4>(a); intra<2, 2>(a); intra<1, 1>(a);
  intra<63, 32>(a); intra<16, 16>(a); intra<8, 8>(a); intra<4, 4>(a);
  intra<2, 2>(a); intra<1, 1>(a);
#define CLEAN6 intra<32, 32>(a); intra<16, 16>(a); intra<8, 8>(a); \
               intra<4, 4>(a); intra<2, 2>(a); intra<1, 1>(a)
  // s7 -> 128-runs
  fdpp<DPP_X1>(a, !(t & 1)); CLEAN6;
  // s8 -> 256
  fdpp<DPP_X3>(a, !(t & 2)); cdpp<DPP_X1>(a, !(t & 1)); CLEAN6;
  // s9 -> 512
  fdpp<DPP_X7>(a, !(t & 4)); cdpp<DPP_X2>(a, !(t & 2)); cdpp<DPP_X1>(a, !(t & 1)); CLEAN6;
  // s10 -> 1024
  fdpp<DPP_XF>(a, !(t & 8)); cbp(a, 4, !(t & 4), t);
  cdpp<DPP_X2>(a, !(t & 2)); cdpp<DPP_X1>(a, !(t & 1)); CLEAN6;
  // s11 -> 2048
  fbp(a, 31, !(t & 16), t); cdpp<DPP_X8>(a, !(t & 8)); cbp(a, 4, !(t & 4), t);
  cdpp<DPP_X2>(a, !(t & 2)); cdpp<DPP_X1>(a, !(t & 1)); CLEAN6;
  // s12 -> 4096
  fbp(a, 63, !(t & 32), t); cbp(a, 16, !(t & 16), t); cdpp<DPP_X8>(a, !(t & 8));
  cbp(a, 4, !(t & 4), t); cdpp<DPP_X2>(a, !(t & 2)); cdpp<DPP_X1>(a, !(t & 1)); CLEAN6;
#undef CLEAN6
  // rank-weighted sum: rank of a[e] is 64t+e; lo half -> o0, hi half -> o1
  const float4* pw0 = (const float4*)(pwt + (size_t)o0 * 4096 + t * 64);
  const float4* pw1 = (const float4*)(pwt + (size_t)o1 * 4096 + t * 64);
  float s0 = 0.f, s1 = 0.f;
#pragma unroll
  for (int q = 0; q < 16; ++q) {
    float4 w0 = pw0[q], w1 = pw1[q];
    float k0[4] = {w0.x, w0.y, w0.z, w0.w};
    float k1[4] = {w1.x, w1.y, w1.z, w1.w};
#pragma unroll
    for (int r = 0; r < 4; ++r) {
      h2 v2 = ih2(a[q * 4 + r]);
      s0 = fmaf((float)v2[0], k0[r], s0);
      s1 = fmaf((float)v2[1], k1[r], s1);
    }
  }
#pragma unroll
  for (int off = 32; off > 0; off >>= 1) {
    s0 += __shfl_xor(s0, off);
    s1 += __shfl_xor(s1, off);
  }
  if (t == 0) {
    out[b * 256 + o0] = s0;
    out[b * 256 + o1] = s1;
  }
}

extern "C" void kernel_launch(void* const* d_in, const int* in_sizes, int n_in,
                              void* d_out, int out_size, void* d_ws, size_t ws_size,
                              hipStream_t stream) {
  const float* x  = (const float*)d_in[0];
  const float* w1 = (const float*)d_in[1];
  const float* b1 = (const float*)d_in[2];
  const float* w2 = (const float*)d_in[3];
  const float* b2 = (const float*)d_in[4];
  const float* pw = (const float*)d_in[5];
  char* ws = (char*)d_ws;
  _Float16* u   = (_Float16*)ws;                                   // 2 MiB
  _Float16* v   = (_Float16*)(ws + (2u << 20));                    // 2 MiB
  _Float16* w2t = (_Float16*)(ws + (4u << 20));                    // 256 KiB
  float*    pwt = (float*)(ws + (5u << 20));                       // 4 MiB
  unsigned short* yt = (unsigned short*)(ws + (9u << 20));         // 64 MiB f16
  float* out = (float*)d_out;

  k_prep<<<dim3(768), dim3(256), 0, stream>>>(x, w1, b1, w2, pw, u, v, w2t, pwt);
  k_gemm<<<dim3(2048), dim3(256), 0, stream>>>(u, v, w2t, b2, yt);
  k_sortpool<<<dim3(4096), dim3(64), 0, stream>>>(yt, pwt, out);
}

// Round 14
// 171.341 us; speedup vs baseline: 1.3407x; 1.3407x over previous
//
#include <hip/hip_runtime.h>
#include <hip/hip_bf16.h>
#include <hip/hip_fp16.h>

typedef __attribute__((ext_vector_type(4))) float f32x4;
typedef _Float16 h8 __attribute__((ext_vector_type(8)));
typedef int i32x4 __attribute__((ext_vector_type(4)));
typedef _Float16 h2 __attribute__((ext_vector_type(2)));

static __device__ __forceinline__ h2 ih2(int x) { return __builtin_bit_cast(h2, x); }
static __device__ __forceinline__ unsigned pkrtz(float lo, float hi) {
  return __builtin_bit_cast(unsigned, __builtin_amdgcn_cvt_pkrtz(lo, hi));
}
// inline-asm packed f16 ops
static __device__ __forceinline__ int pkmin(int x, int y) {
  int d; asm("v_pk_min_f16 %0, %1, %2" : "=v"(d) : "v"(x), "v"(y)); return d;
}
static __device__ __forceinline__ int pkmax(int x, int y) {
  int d; asm("v_pk_max_f16 %0, %1, %2" : "=v"(d) : "v"(x), "v"(y)); return d;
}
static __device__ __forceinline__ int pkadd(int x, int y) {
  int d; asm("v_pk_add_f16 %0, %1, %2" : "=v"(d) : "v"(x), "v"(y)); return d;
}

// Problem constants: B=32, L=64, C=128, D=512, O=256, L2=4096

// ------ K1 (fused prep): u,v = f16(x@w1 split + b1); w2t; pwt ------------
__global__ __launch_bounds__(256) void k_prep(const float* __restrict__ x,
                                              const float* __restrict__ w1,
                                              const float* __restrict__ b1,
                                              const float* __restrict__ w2,
                                              const float* __restrict__ pw,
                                              _Float16* __restrict__ u,
                                              _Float16* __restrict__ v,
                                              _Float16* __restrict__ w2t,
                                              float* __restrict__ pwt) {
  __shared__ float xs[8 * 128];
  int bid = blockIdx.x;
  int t = threadIdx.x;
  if (bid < 256) {
    int r0 = bid * 8;
    ((float4*)xs)[t] = ((const float4*)(x + (size_t)r0 * 128))[t];
    __syncthreads();
    int d1 = t, d2 = t + 256;
    float au0[8], au1[8], av0[8], av1[8];
    float bb1 = b1[d1], bb2 = b1[d2];
#pragma unroll
    for (int r = 0; r < 8; ++r) { au0[r] = bb1; au1[r] = bb2; av0[r] = 0.f; av1[r] = 0.f; }
#pragma unroll 4
    for (int c = 0; c < 128; ++c) {
      float wu1 = w1[c * 512 + d1];
      float wu2 = w1[c * 512 + d2];
      float wv1 = w1[(c + 128) * 512 + d1];
      float wv2 = w1[(c + 128) * 512 + d2];
#pragma unroll
      for (int r = 0; r < 8; ++r) {
        float xv = xs[r * 128 + c];
        au0[r] = fmaf(xv, wu1, au0[r]);
        au1[r] = fmaf(xv, wu2, au1[r]);
        av0[r] = fmaf(xv, wv1, av0[r]);
        av1[r] = fmaf(xv, wv2, av1[r]);
      }
    }
#pragma unroll
    for (int r = 0; r < 8; ++r) {
      u[(size_t)(r0 + r) * 512 + d1] = (_Float16)au0[r];
      u[(size_t)(r0 + r) * 512 + d2] = (_Float16)au1[r];
      v[(size_t)(r0 + r) * 512 + d1] = (_Float16)av0[r];
      v[(size_t)(r0 + r) * 512 + d2] = (_Float16)av1[r];
    }
  } else if (bid < 512) {
    int n = bid - 256;
    w2t[(size_t)n * 512 + t]       = (_Float16)w2[(size_t)t * 256 + n];
    w2t[(size_t)n * 512 + t + 256] = (_Float16)w2[(size_t)(t + 256) * 256 + n];
  } else {
    int o = bid - 512;
#pragma unroll
    for (int it = 0; it < 16; ++it) {
      int l = it * 256 + t;
      pwt[(size_t)o * 4096 + l] = pw[(size_t)l * 256 + o];
    }
  }
}

// ---- K4: j-split register-built h -> f16 MFMA -> f16 y^T ---------------
// block = (b, ig in 0..7 of 4 i-rows, jh half of j); LDS 36 KiB -> 4 blk/CU
__global__ __launch_bounds__(256, 2) void k_gemm(const _Float16* __restrict__ u,
                                                 const _Float16* __restrict__ v,
                                                 const _Float16* __restrict__ w2t,
                                                 const float* __restrict__ b2,
                                                 unsigned short* __restrict__ yt) {
  __shared__ char vl[32 * 1024];  // 32 j-rows x 512 f16, XOR-swizzled
  __shared__ char ulm[4 * 1024];  // 4 u-rows x 512 f16
  int t = threadIdx.x;
  int n0 = blockIdx.x;                      // 1024 blocks
  int bid = (n0 & 7) * 128 + (n0 >> 3);     // XCD-bijective: same-b same XCD
  int b = bid >> 5, rest = bid & 31;
  int ig = rest >> 1, jh = rest & 1;
  {
    const char* vsrc = (const char*)(v + (size_t)(b * 64 + jh * 32) * 512);
#pragma unroll
    for (int it = 0; it < 8; ++it) {
      int f = it * 4096 + t * 16;
      uint4 d = *(const uint4*)(vsrc + f);
      int row = f >> 10;
      *(uint4*)(vl + (f ^ ((row & 7) << 4))) = d;
    }
    const char* usrc = (const char*)(u + (size_t)(b * 64 + ig * 4) * 512);
    *(uint4*)(ulm + t * 16) = *(const uint4*)(usrc + t * 16);
  }
  __syncthreads();
  int w = t >> 6, l = t & 63, lr = l & 15, lg = l >> 4;
  const _Float16* bptr[4];
  float bias[4];
#pragma unroll
  for (int ni = 0; ni < 4; ++ni) {
    int col = w * 64 + ni * 16 + lr;
    bptr[ni] = w2t + (size_t)col * 512 + lg * 8;
    bias[ni] = b2[col];
  }
#pragma unroll 1
  for (int ih = 0; ih < 2; ++ih) {  // i-pairs: i = ig*4 + ih*2 + {0,1}
    f32x4 acc[2][2][4];
#pragma unroll
    for (int ip = 0; ip < 2; ++ip)
#pragma unroll
      for (int mi = 0; mi < 2; ++mi)
#pragma unroll
        for (int ni = 0; ni < 4; ++ni) {
          float bv = bias[ni];
          f32x4 ci = {bv, bv, bv, bv};
          acc[ip][mi][ni] = ci;
        }
#pragma unroll 2
    for (int kk = 0; kk < 16; ++kk) {
      h8 bfv[4];
#pragma unroll
      for (int ni = 0; ni < 4; ++ni) bfv[ni] = *(const h8*)(bptr[ni] + kk * 32);
      i32x4 vf[2];
#pragma unroll
      for (int mi = 0; mi < 2; ++mi) {
        int row = mi * 16 + lr;
        int fb = row * 1024 + kk * 64 + lg * 16;
        vf[mi] = *(const i32x4*)(vl + (fb ^ ((row & 7) << 4)));
      }
#pragma unroll
      for (int ip = 0; ip < 2; ++ip) {
        i32x4 uf = *(const i32x4*)(ulm + (ih * 2 + ip) * 1024 + kk * 64 + lg * 16);
#pragma unroll
        for (int mi = 0; mi < 2; ++mi) {
          i32x4 aw;
#pragma unroll
          for (int q = 0; q < 4; ++q) aw[q] = pkmax(pkadd(uf[q], vf[mi][q]), 0);
          h8 af = __builtin_bit_cast(h8, aw);
#pragma unroll
          for (int ni = 0; ni < 4; ++ni)
            acc[ip][mi][ni] =
                __builtin_amdgcn_mfma_f32_16x16x32_f16(af, bfv[ni], acc[ip][mi][ni], 0, 0, 0);
        }
      }
    }
    // epilogue: n = col (lane&15), j = jh*32 + mi*16 + lg*4 + reg
#pragma unroll
    for (int ip = 0; ip < 2; ++ip) {
      int i = ig * 4 + ih * 2 + ip;
#pragma unroll
      for (int mi = 0; mi < 2; ++mi)
#pragma unroll
        for (int ni = 0; ni < 4; ++ni) {
          int col = w * 64 + ni * 16 + lr;
          unsigned short* colbase =
              yt + (size_t)(b * 256 + col) * 4096 + (size_t)i * 64 + jh * 32 + mi * 16 + lg * 4;
          f32x4 vv = acc[ip][mi][ni];
          uint2 st;
          st.x = pkrtz(vv[0], vv[1]);
          st.y = pkrtz(vv[2], vv[3]);
          *(uint2*)colbase = st;
        }
    }
  }
}

// ----- K5: E=64 single-wave packed-f16 bitonic sort + pool (no LDS) -----
#define DPP_X1 0xB1   // quad_perm [1,0,3,2]  : lane^1
#define DPP_X2 0x4E   // quad_perm [2,3,0,1]  : lane^2
#define DPP_X3 0x1B   // quad_perm [3,2,1,0]  : lane^3
#define DPP_X7 0x141  // row_half_mirror      : lane^7
#define DPP_X8 0x128  // row_ror:8            : lane^8
#define DPP_XF 0x140  // row_mirror           : lane^15

// intra-register CE pass: pairs (e, e^M), min at low index
template <int M, int HB>
static __device__ __forceinline__ void intra(int* a) {
#pragma unroll
  for (int e = 0; e < 64; ++e)
    if ((e & HB) == 0) {
      int f = e ^ M;
      int lo = pkmin(a[e], a[f]);
      int hi = pkmax(a[e], a[f]);
      a[e] = lo;
      a[f] = hi;
    }
}

// clean cross pass via DPP (same e, partner lane)
template <int CTRL>
static __device__ __forceinline__ void cdpp(int* a, bool km) {
#pragma unroll
  for (int e = 0; e < 64; ++e) {
    int r = __builtin_amdgcn_mov_dpp(a[e], CTRL, 0xf, 0xf, true);
    int mn = pkmin(a[e], r), mx = pkmax(a[e], r);
    a[e] = km ? mn : mx;
  }
}

// flip cross pass via DPP (e^63, partner lane)
template <int CTRL>
static __device__ __forceinline__ void fdpp(int* a, bool km) {
#pragma unroll
  for (int e = 0; e < 32; ++e) {
    int f = e ^ 63;
    int r0 = __builtin_amdgcn_mov_dpp(a[f], CTRL, 0xf, 0xf, true);
    int r1 = __builtin_amdgcn_mov_dpp(a[e], CTRL, 0xf, 0xf, true);
    int mn0 = pkmin(a[e], r0), mx0 = pkmax(a[e], r0);
    int mn1 = pkmin(a[f], r1), mx1 = pkmax(a[f], r1);
    a[e] = km ? mn0 : mx0;
    a[f] = km ? mn1 : mx1;
  }
}

// clean cross pass via ds_bpermute
static __device__ __forceinline__ void cbp(int* a, int tm, bool km, int l) {
  int paddr = ((l ^ tm) & 63) << 2;
#pragma unroll
  for (int e = 0; e < 64; ++e) {
    int r = __builtin_amdgcn_ds_bpermute(paddr, a[e]);
    int mn = pkmin(a[e], r), mx = pkmax(a[e], r);
    a[e] = km ? mn : mx;
  }
}

// flip cross pass via ds_bpermute (e^63)
static __device__ __forceinline__ void fbp(int* a, int tm, bool km, int l) {
  int paddr = ((l ^ tm) & 63) << 2;
#pragma unroll
  for (int e = 0; e < 32; ++e) {
    int f = e ^ 63;
    int r0 = __builtin_amdgcn_ds_bpermute(paddr, a[f]);
    int r1 = __builtin_amdgcn_ds_bpermute(paddr, a[e]);
    int mn0 = pkmin(a[e], r0), mx0 = pkmax(a[e], r0);
    int mn1 = pkmin(a[f], r1), mx1 = pkmax(a[f], r1);
    a[e] = km ? mn0 : mx0;
    a[f] = km ? mn1 : mx1;
  }
}

__global__ __launch_bounds__(64) void k_sortpool(const unsigned short* __restrict__ yt,
                                                 const float* __restrict__ pwt,
                                                 float* __restrict__ out) {
  int t = threadIdx.x;  // lane 0..63 (one wave per block)
  int b = blockIdx.x >> 7, p = blockIdx.x & 127;
  int o0 = p * 2, o1 = o0 + 1;
  const uint4* c0 = (const uint4*)(yt + (size_t)(b * 256 + o0) * 4096 + t * 64);
  const uint4* c1 = (const uint4*)(yt + (size_t)(b * 256 + o1) * 4096 + t * 64);
  int a[64];
#pragma unroll
  for (int q = 0; q < 8; ++q) {  // 8 elems per uint4 per column
    uint4 x0 = c0[q], x1 = c1[q];
    unsigned w0[4] = {x0.x, x0.y, x0.z, x0.w};
    unsigned w1[4] = {x1.x, x1.y, x1.z, x1.w};
#pragma unroll
    for (int r = 0; r < 4; ++r) {
      a[q * 8 + 2 * r]     = (int)((w0[r] & 0xffffu) | (w1[r] << 16));
      a[q * 8 + 2 * r + 1] = (int)((w0[r] >> 16) | (w1[r] & 0xffff0000u));
    }
  }
  // stages s1..s6 (runs <= 64): pure in-register
  intra<1, 1>(a);
  intra<3, 2>(a); intra<1, 1>(a);
  intra<7, 4>(a); intra<2, 2>(a); intra<1, 1>(a);
  intra<15, 8>(a); intra<4, 4>(a); intra<2, 2>(a); intra<1, 1>(a);
  intra<31, 16>(a); intra<8, 8>(a); intra<4, 4>(a); intra<2, 2>(a); intra<1, 1>(a);
  intra<63, 32>(a); intra<16, 16>(a); intra<8, 8>(a); intra<4, 4>(a);
  intra<2, 2>(a); intra<1, 1>(a);
#define CLEAN6 intra<32, 32>(a); intra<16, 16>(a); intra<8, 8>(a); \
               intra<4, 4>(a); intra<2, 2>(a); intra<1, 1>(a)
  // s7 -> 128-runs
  fdpp<DPP_X1>(a, !(t & 1)); CLEAN6;
  // s8 -> 256
  fdpp<DPP_X3>(a, !(t & 2)); cdpp<DPP_X1>(a, !(t & 1)); CLEAN6;
  // s9 -> 512
  fdpp<DPP_X7>(a, !(t & 4)); cdpp<DPP_X2>(a, !(t & 2)); cdpp<DPP_X1>(a, !(t & 1)); CLEAN6;
  // s10 -> 1024
  fdpp<DPP_XF>(a, !(t & 8)); cbp(a, 4, !(t & 4), t);
  cdpp<DPP_X2>(a, !(t & 2)); cdpp<DPP_X1>(a, !(t & 1)); CLEAN6;
  // s11 -> 2048
  fbp(a, 31, !(t & 16), t); cdpp<DPP_X8>(a, !(t & 8)); cbp(a, 4, !(t & 4), t);
  cdpp<DPP_X2>(a, !(t & 2)); cdpp<DPP_X1>(a, !(t & 1)); CLEAN6;
  // s12 -> 4096
  fbp(a, 63, !(t & 32), t); cbp(a, 16, !(t & 16), t); cdpp<DPP_X8>(a, !(t & 8));
  cbp(a, 4, !(t & 4), t); cdpp<DPP_X2>(a, !(t & 2)); cdpp<DPP_X1>(a, !(t & 1)); CLEAN6;
#undef CLEAN6
  // rank-weighted sum: rank of a[e] is 64t+e; lo half -> o0, hi half -> o1
  const float4* pw0 = (const float4*)(pwt + (size_t)o0 * 4096 + t * 64);
  const float4* pw1 = (const float4*)(pwt + (size_t)o1 * 4096 + t * 64);
  float s0 = 0.f, s1 = 0.f;
#pragma unroll
  for (int q = 0; q < 16; ++q) {
    float4 w0 = pw0[q], w1 = pw1[q];
    float k0[4] = {w0.x, w0.y, w0.z, w0.w};
    float k1[4] = {w1.x, w1.y, w1.z, w1.w};
#pragma unroll
    for (int r = 0; r < 4; ++r) {
      h2 v2 = ih2(a[q * 4 + r]);
      s0 = fmaf((float)v2[0], k0[r], s0);
      s1 = fmaf((float)v2[1], k1[r], s1);
    }
  }
#pragma unroll
  for (int off = 32; off > 0; off >>= 1) {
    s0 += __shfl_xor(s0, off);
    s1 += __shfl_xor(s1, off);
  }
  if (t == 0) {
    out[b * 256 + o0] = s0;
    out[b * 256 + o1] = s1;
  }
}

extern "C" void kernel_launch(void* const* d_in, const int* in_sizes, int n_in,
                              void* d_out, int out_size, void* d_ws, size_t ws_size,
                              hipStream_t stream) {
  const float* x  = (const float*)d_in[0];
  const float* w1 = (const float*)d_in[1];
  const float* b1 = (const float*)d_in[2];
  const float* w2 = (const float*)d_in[3];
  const float* b2 = (const float*)d_in[4];
  const float* pw = (const float*)d_in[5];
  char* ws = (char*)d_ws;
  _Float16* u   = (_Float16*)ws;                                   // 2 MiB
  _Float16* v   = (_Float16*)(ws + (2u << 20));                    // 2 MiB
  _Float16* w2t = (_Float16*)(ws + (4u << 20));                    // 256 KiB
  float*    pwt = (float*)(ws + (5u << 20));                       // 4 MiB
  unsigned short* yt = (unsigned short*)(ws + (9u << 20));         // 64 MiB f16
  float* out = (float*)d_out;

  k_prep<<<dim3(768), dim3(256), 0, stream>>>(x, w1, b1, w2, pw, u, v, w2t, pwt);
  k_gemm<<<dim3(1024), dim3(256), 0, stream>>>(u, v, w2t, b2, yt);
  k_sortpool<<<dim3(4096), dim3(64), 0, stream>>>(yt, pwt, out);
}

// Round 15
// 146.161 us; speedup vs baseline: 1.5716x; 1.1723x over previous
//
#include <hip/hip_runtime.h>
#include <hip/hip_bf16.h>
#include <hip/hip_fp16.h>

typedef __attribute__((ext_vector_type(4))) float f32x4;
typedef _Float16 h8 __attribute__((ext_vector_type(8)));
typedef int i32x4 __attribute__((ext_vector_type(4)));
typedef _Float16 h2 __attribute__((ext_vector_type(2)));

static __device__ __forceinline__ h2 ih2(int x) { return __builtin_bit_cast(h2, x); }
static __device__ __forceinline__ unsigned pkrtz(float lo, float hi) {
  return __builtin_bit_cast(unsigned, __builtin_amdgcn_cvt_pkrtz(lo, hi));
}
// inline-asm packed f16 ops
static __device__ __forceinline__ int pkmin(int x, int y) {
  int d; asm("v_pk_min_f16 %0, %1, %2" : "=v"(d) : "v"(x), "v"(y)); return d;
}
static __device__ __forceinline__ int pkmax(int x, int y) {
  int d; asm("v_pk_max_f16 %0, %1, %2" : "=v"(d) : "v"(x), "v"(y)); return d;
}
static __device__ __forceinline__ int pkadd(int x, int y) {
  int d; asm("v_pk_add_f16 %0, %1, %2" : "=v"(d) : "v"(x), "v"(y)); return d;
}

// Problem constants: B=32, L=64, C=128, D=512, O=256, L2=4096

// ------ K1 (fused prep): u,v = f16(x@w1 split + b1); w2t; pwt ------------
__global__ __launch_bounds__(256) void k_prep(const float* __restrict__ x,
                                              const float* __restrict__ w1,
                                              const float* __restrict__ b1,
                                              const float* __restrict__ w2,
                                              const float* __restrict__ pw,
                                              _Float16* __restrict__ u,
                                              _Float16* __restrict__ v,
                                              _Float16* __restrict__ w2t,
                                              float* __restrict__ pwt) {
  __shared__ float xs[8 * 128];
  int bid = blockIdx.x;
  int t = threadIdx.x;
  if (bid < 256) {
    int r0 = bid * 8;
    ((float4*)xs)[t] = ((const float4*)(x + (size_t)r0 * 128))[t];
    __syncthreads();
    int d1 = t, d2 = t + 256;
    float au0[8], au1[8], av0[8], av1[8];
    float bb1 = b1[d1], bb2 = b1[d2];
#pragma unroll
    for (int r = 0; r < 8; ++r) { au0[r] = bb1; au1[r] = bb2; av0[r] = 0.f; av1[r] = 0.f; }
#pragma unroll 4
    for (int c = 0; c < 128; ++c) {
      float wu1 = w1[c * 512 + d1];
      float wu2 = w1[c * 512 + d2];
      float wv1 = w1[(c + 128) * 512 + d1];
      float wv2 = w1[(c + 128) * 512 + d2];
#pragma unroll
      for (int r = 0; r < 8; ++r) {
        float xv = xs[r * 128 + c];
        au0[r] = fmaf(xv, wu1, au0[r]);
        au1[r] = fmaf(xv, wu2, au1[r]);
        av0[r] = fmaf(xv, wv1, av0[r]);
        av1[r] = fmaf(xv, wv2, av1[r]);
      }
    }
#pragma unroll
    for (int r = 0; r < 8; ++r) {
      u[(size_t)(r0 + r) * 512 + d1] = (_Float16)au0[r];
      u[(size_t)(r0 + r) * 512 + d2] = (_Float16)au1[r];
      v[(size_t)(r0 + r) * 512 + d1] = (_Float16)av0[r];
      v[(size_t)(r0 + r) * 512 + d2] = (_Float16)av1[r];
    }
  } else if (bid < 512) {
    int n = bid - 256;
    w2t[(size_t)n * 512 + t]       = (_Float16)w2[(size_t)t * 256 + n];
    w2t[(size_t)n * 512 + t + 256] = (_Float16)w2[(size_t)(t + 256) * 256 + n];
  } else {
    int o = bid - 512;
#pragma unroll
    for (int it = 0; it < 16; ++it) {
      int l = it * 256 + t;
      pwt[(size_t)o * 4096 + l] = pw[(size_t)l * 256 + o];
    }
  }
}

// ---- K4: register-built h = relu(u_i + v_j) -> f16 MFMA -> f16 y^T -----
// 512 blocks: (b, ig of 4 i-rows); v-tile 64x512 f16 staged once, 1 barrier
__global__ __launch_bounds__(256, 2) void k_gemm(const _Float16* __restrict__ u,
                                                 const _Float16* __restrict__ v,
                                                 const _Float16* __restrict__ w2t,
                                                 const float* __restrict__ b2,
                                                 unsigned short* __restrict__ yt) {
  __shared__ char vl[64 * 1024];  // 64 rows x 512 f16, XOR-swizzled
  __shared__ char ulm[4 * 1024];  // 4 u-rows x 512 f16
  int t = threadIdx.x;
  int n0 = blockIdx.x;                     // 512 blocks
  int bid = (n0 & 7) * 64 + (n0 >> 3);     // XCD-bijective: same-b same XCD
  int b = bid >> 4, ig = bid & 15;
  {
    const char* vsrc = (const char*)(v + (size_t)b * 64 * 512);
#pragma unroll
    for (int it = 0; it < 16; ++it) {
      int f = it * 4096 + t * 16;
      uint4 d = *(const uint4*)(vsrc + f);
      int row = f >> 10;
      *(uint4*)(vl + (f ^ ((row & 7) << 4))) = d;
    }
    const char* usrc = (const char*)(u + (size_t)(b * 64 + ig * 4) * 512);
    int f = t * 16;
    *(uint4*)(ulm + f) = *(const uint4*)(usrc + f);
  }
  __syncthreads();
  int w = t >> 6, l = t & 63, lr = l & 15, lg = l >> 4;
  const _Float16* bptr[4];
  float bias[4];
#pragma unroll
  for (int ni = 0; ni < 4; ++ni) {
    int col = w * 64 + ni * 16 + lr;
    bptr[ni] = w2t + (size_t)col * 512 + lg * 8;
    bias[ni] = b2[col];
  }
#pragma unroll 1
  for (int ih = 0; ih < 2; ++ih) {  // i-pairs: i = ig*4 + ih*2 + {0,1}
    f32x4 acc[2][4][4];
#pragma unroll
    for (int ip = 0; ip < 2; ++ip)
#pragma unroll
      for (int mi = 0; mi < 4; ++mi)
#pragma unroll
        for (int ni = 0; ni < 4; ++ni) {
          float bv = bias[ni];
          f32x4 ci = {bv, bv, bv, bv};
          acc[ip][mi][ni] = ci;
        }
#pragma unroll 2
    for (int kk = 0; kk < 16; ++kk) {
      h8 bfv[4];
#pragma unroll
      for (int ni = 0; ni < 4; ++ni) bfv[ni] = *(const h8*)(bptr[ni] + kk * 32);
      i32x4 vf[4];
#pragma unroll
      for (int mi = 0; mi < 4; ++mi) {
        int row = mi * 16 + lr;
        int fb = row * 1024 + kk * 64 + lg * 16;
        vf[mi] = *(const i32x4*)(vl + (fb ^ ((row & 7) << 4)));
      }
#pragma unroll
      for (int ip = 0; ip < 2; ++ip) {
        i32x4 uf = *(const i32x4*)(ulm + (ih * 2 + ip) * 1024 + kk * 64 + lg * 16);
#pragma unroll
        for (int mi = 0; mi < 4; ++mi) {
          i32x4 aw;
#pragma unroll
          for (int q = 0; q < 4; ++q) aw[q] = pkmax(pkadd(uf[q], vf[mi][q]), 0);
          h8 af = __builtin_bit_cast(h8, aw);
#pragma unroll
          for (int ni = 0; ni < 4; ++ni)
            acc[ip][mi][ni] =
                __builtin_amdgcn_mfma_f32_16x16x32_f16(af, bfv[ni], acc[ip][mi][ni], 0, 0, 0);
        }
      }
    }
#pragma unroll
    for (int ip = 0; ip < 2; ++ip) {
      int i = ig * 4 + ih * 2 + ip;
#pragma unroll
      for (int ni = 0; ni < 4; ++ni) {
        int col = w * 64 + ni * 16 + lr;
        unsigned short* colbase = yt + (size_t)(b * 256 + col) * 4096 + (size_t)i * 64;
#pragma unroll
        for (int mi = 0; mi < 4; ++mi) {
          f32x4 vv = acc[ip][mi][ni];
          uint2 st;
          st.x = pkrtz(vv[0], vv[1]);
          st.y = pkrtz(vv[2], vv[3]);
          *(uint2*)(colbase + mi * 16 + lg * 4) = st;
        }
      }
    }
  }
}

// ----- K5: E=64 single-wave packed-f16 bitonic sort + pool (no LDS) -----
#define DPP_X1 0xB1   // quad_perm [1,0,3,2]  : lane^1
#define DPP_X2 0x4E   // quad_perm [2,3,0,1]  : lane^2
#define DPP_X3 0x1B   // quad_perm [3,2,1,0]  : lane^3
#define DPP_X7 0x141  // row_half_mirror      : lane^7
#define DPP_X8 0x128  // row_ror:8            : lane^8
#define DPP_XF 0x140  // row_mirror           : lane^15

// intra-register CE pass: pairs (e, e^M), min at low index
template <int M, int HB>
static __device__ __forceinline__ void intra(int* a) {
#pragma unroll
  for (int e = 0; e < 64; ++e)
    if ((e & HB) == 0) {
      int f = e ^ M;
      int lo = pkmin(a[e], a[f]);
      int hi = pkmax(a[e], a[f]);
      a[e] = lo;
      a[f] = hi;
    }
}

// clean cross pass via DPP (same e, partner lane)
template <int CTRL>
static __device__ __forceinline__ void cdpp(int* a, bool km) {
#pragma unroll
  for (int e = 0; e < 64; ++e) {
    int r = __builtin_amdgcn_mov_dpp(a[e], CTRL, 0xf, 0xf, true);
    int mn = pkmin(a[e], r), mx = pkmax(a[e], r);
    a[e] = km ? mn : mx;
  }
}

// flip cross pass via DPP (e^63, partner lane)
template <int CTRL>
static __device__ __forceinline__ void fdpp(int* a, bool km) {
#pragma unroll
  for (int e = 0; e < 32; ++e) {
    int f = e ^ 63;
    int r0 = __builtin_amdgcn_mov_dpp(a[f], CTRL, 0xf, 0xf, true);
    int r1 = __builtin_amdgcn_mov_dpp(a[e], CTRL, 0xf, 0xf, true);
    int mn0 = pkmin(a[e], r0), mx0 = pkmax(a[e], r0);
    int mn1 = pkmin(a[f], r1), mx1 = pkmax(a[f], r1);
    a[e] = km ? mn0 : mx0;
    a[f] = km ? mn1 : mx1;
  }
}

// clean cross pass via ds_bpermute
static __device__ __forceinline__ void cbp(int* a, int tm, bool km, int l) {
  int paddr = ((l ^ tm) & 63) << 2;
#pragma unroll
  for (int e = 0; e < 64; ++e) {
    int r = __builtin_amdgcn_ds_bpermute(paddr, a[e]);
    int mn = pkmin(a[e], r), mx = pkmax(a[e], r);
    a[e] = km ? mn : mx;
  }
}

// flip cross pass via ds_bpermute (e^63)
static __device__ __forceinline__ void fbp(int* a, int tm, bool km, int l) {
  int paddr = ((l ^ tm) & 63) << 2;
#pragma unroll
  for (int e = 0; e < 32; ++e) {
    int f = e ^ 63;
    int r0 = __builtin_amdgcn_ds_bpermute(paddr, a[f]);
    int r1 = __builtin_amdgcn_ds_bpermute(paddr, a[e]);
    int mn0 = pkmin(a[e], r0), mx0 = pkmax(a[e], r0);
    int mn1 = pkmin(a[f], r1), mx1 = pkmax(a[f], r1);
    a[e] = km ? mn0 : mx0;
    a[f] = km ? mn1 : mx1;
  }
}

__global__ __launch_bounds__(64) void k_sortpool(const unsigned short* __restrict__ yt,
                                                 const float* __restrict__ pwt,
                                                 float* __restrict__ out) {
  int t = threadIdx.x;  // lane 0..63 (one wave per block)
  int b = blockIdx.x >> 7, p = blockIdx.x & 127;
  int o0 = p * 2, o1 = o0 + 1;
  const uint4* c0 = (const uint4*)(yt + (size_t)(b * 256 + o0) * 4096 + t * 64);
  const uint4* c1 = (const uint4*)(yt + (size_t)(b * 256 + o1) * 4096 + t * 64);
  int a[64];
#pragma unroll
  for (int q = 0; q < 8; ++q) {  // 8 elems per uint4 per column
    uint4 x0 = c0[q], x1 = c1[q];
    unsigned w0[4] = {x0.x, x0.y, x0.z, x0.w};
    unsigned w1[4] = {x1.x, x1.y, x1.z, x1.w};
#pragma unroll
    for (int r = 0; r < 4; ++r) {
      a[q * 8 + 2 * r]     = (int)((w0[r] & 0xffffu) | (w1[r] << 16));
      a[q * 8 + 2 * r + 1] = (int)((w0[r] >> 16) | (w1[r] & 0xffff0000u));
    }
  }
  // stages s1..s6 (runs <= 64): pure in-register
  intra<1, 1>(a);
  intra<3, 2>(a); intra<1, 1>(a);
  intra<7, 4>(a); intra<2, 2>(a); intra<1, 1>(a);
  intra<15, 8>(a); intra<4, 4>(a); intra<2, 2>(a); intra<1, 1>(a);
  intra<31, 16>(a); intra<8, 8>(a); intra<4, 4>(a); intra<2, 2>(a); intra<1, 1>(a);
  intra<63, 32>(a); intra<16, 16>(a); intra<8, 8>(a); intra<4, 4>(a);
  intra<2, 2>(a); intra<1, 1>(a);
#define CLEAN6 intra<32, 32>(a); intra<16, 16>(a); intra<8, 8>(a); \
               intra<4, 4>(a); intra<2, 2>(a); intra<1, 1>(a)
  // s7 -> 128-runs
  fdpp<DPP_X1>(a, !(t & 1)); CLEAN6;
  // s8 -> 256
  fdpp<DPP_X3>(a, !(t & 2)); cdpp<DPP_X1>(a, !(t & 1)); CLEAN6;
  // s9 -> 512
  fdpp<DPP_X7>(a, !(t & 4)); cdpp<DPP_X2>(a, !(t & 2)); cdpp<DPP_X1>(a, !(t & 1)); CLEAN6;
  // s10 -> 1024
  fdpp<DPP_XF>(a, !(t & 8)); cbp(a, 4, !(t & 4), t);
  cdpp<DPP_X2>(a, !(t & 2)); cdpp<DPP_X1>(a, !(t & 1)); CLEAN6;
  // s11 -> 2048
  fbp(a, 31, !(t & 16), t); cdpp<DPP_X8>(a, !(t & 8)); cbp(a, 4, !(t & 4), t);
  cdpp<DPP_X2>(a, !(t & 2)); cdpp<DPP_X1>(a, !(t & 1)); CLEAN6;
  // s12 -> 4096
  fbp(a, 63, !(t & 32), t); cbp(a, 16, !(t & 16), t); cdpp<DPP_X8>(a, !(t & 8));
  cbp(a, 4, !(t & 4), t); cdpp<DPP_X2>(a, !(t & 2)); cdpp<DPP_X1>(a, !(t & 1)); CLEAN6;
#undef CLEAN6
  // rank-weighted sum: rank of a[e] is 64t+e; lo half -> o0, hi half -> o1
  const float4* pw0 = (const float4*)(pwt + (size_t)o0 * 4096 + t * 64);
  const float4* pw1 = (const float4*)(pwt + (size_t)o1 * 4096 + t * 64);
  float s0 = 0.f, s1 = 0.f;
#pragma unroll
  for (int q = 0; q < 16; ++q) {
    float4 w0 = pw0[q], w1 = pw1[q];
    float k0[4] = {w0.x, w0.y, w0.z, w0.w};
    float k1[4] = {w1.x, w1.y, w1.z, w1.w};
#pragma unroll
    for (int r = 0; r < 4; ++r) {
      h2 v2 = ih2(a[q * 4 + r]);
      s0 = fmaf((float)v2[0], k0[r], s0);
      s1 = fmaf((float)v2[1], k1[r], s1);
    }
  }
#pragma unroll
  for (int off = 32; off > 0; off >>= 1) {
    s0 += __shfl_xor(s0, off);
    s1 += __shfl_xor(s1, off);
  }
  if (t == 0) {
    out[b * 256 + o0] = s0;
    out[b * 256 + o1] = s1;
  }
}

extern "C" void kernel_launch(void* const* d_in, const int* in_sizes, int n_in,
                              void* d_out, int out_size, void* d_ws, size_t ws_size,
                              hipStream_t stream) {
  const float* x  = (const float*)d_in[0];
  const float* w1 = (const float*)d_in[1];
  const float* b1 = (const float*)d_in[2];
  const float* w2 = (const float*)d_in[3];
  const float* b2 = (const float*)d_in[4];
  const float* pw = (const float*)d_in[5];
  char* ws = (char*)d_ws;
  _Float16* u   = (_Float16*)ws;                                   // 2 MiB
  _Float16* v   = (_Float16*)(ws + (2u << 20));                    // 2 MiB
  _Float16* w2t = (_Float16*)(ws + (4u << 20));                    // 256 KiB
  float*    pwt = (float*)(ws + (5u << 20));                       // 4 MiB
  unsigned short* yt = (unsigned short*)(ws + (9u << 20));         // 64 MiB f16
  float* out = (float*)d_out;

  k_prep<<<dim3(768), dim3(256), 0, stream>>>(x, w1, b1, w2, pw, u, v, w2t, pwt);
  k_gemm<<<dim3(512), dim3(256), 0, stream>>>(u, v, w2t, b2, yt);
  k_sortpool<<<dim3(4096), dim3(64), 0, stream>>>(yt, pwt, out);
}